// Round 7
// baseline (139.479 us; speedup 1.0000x reference)
//
#include <hip/hip_runtime.h>
#include <math.h>

#define D 16
#define K 16
#define BLK 256
#define GRID 1024          // persistent grid-stride over point-groups
#define PK_WORDS 96        // per-cluster param dwords (384 B)
// Param block per cluster k (dword units):
//   [0]      c_k           (f32)  log(pi_k) - sum(log diag L)
//   [1..16]  -t'_i         (f32)  t' = U' mu  (sign folded)
//   [17..88] U' rows       (2xf16 packed, rows padded to even length; 72 words)
//   [89..95] zero pad

typedef _Float16 h2 __attribute__((ext_vector_type(2)));

__host__ __device__ constexpr int tri(int i, int j) { return i * (i + 1) / 2 + j; }
__host__ __device__ constexpr int rowoff(int i) {   // pair-offset of row i
    int s = 0;
    for (int r = 0; r < i; ++r) s += (r + 2) / 2;   // ceil((r+1)/2)
    return s;
}

static __device__ __forceinline__ float fdot2f(h2 a, h2 b, float c) {
#if __has_builtin(__builtin_amdgcn_fdot2)
    return __builtin_amdgcn_fdot2(a, b, c, false);  // v_dot2_f32_f16
#else
    return fmaf((float)a.x, (float)b.x, fmaf((float)a.y, (float)b.y, c));
#endif
}

static __device__ __forceinline__ unsigned pack2(float f0, float f1) {
    _Float16 h0 = (_Float16)f0, h1 = (_Float16)f1;  // RNE converts
    unsigned short b0 = __builtin_bit_cast(unsigned short, h0);
    unsigned short b1 = __builtin_bit_cast(unsigned short, h1);
    return ((unsigned)b1 << 16) | (unsigned)b0;
}

// ---------------------------------------------------------------------------
// Prep: one wave; lane k handles cluster k entirely in registers (~2 us).
// ---------------------------------------------------------------------------
__global__ __launch_bounds__(64) void gmm_prep(
    const float* __restrict__ pi, const float* __restrict__ mu,
    const float* __restrict__ Sigma, float* __restrict__ P)
{
    const int k = threadIdx.x;
    if (k >= K) return;

    float M[tri(D - 1, D - 1) + 1];   // 136 packed lower-tri

#pragma unroll
    for (int i = 0; i < D; ++i)
#pragma unroll
        for (int j = 0; j <= i; ++j)
            M[tri(i, j)] = Sigma[k * D * D + i * D + j];

    // Cholesky, packed, in place.
    float hl = 0.f;
#pragma unroll
    for (int j = 0; j < D; ++j) {
        float s = M[tri(j, j)];
#pragma unroll
        for (int p = 0; p < j; ++p) s -= M[tri(j, p)] * M[tri(j, p)];
        float ljj = sqrtf(s);
        M[tri(j, j)] = ljj;
        hl += logf(ljj);
        float inv = 1.f / ljj;
#pragma unroll
        for (int i = j + 1; i < D; ++i) {
            float t = M[tri(i, j)];
#pragma unroll
            for (int p = 0; p < j; ++p) t -= M[tri(i, p)] * M[tri(j, p)];
            M[tri(i, j)] = t * inv;
        }
    }

    // Invert lower-triangular in place (column j ascending).
#pragma unroll
    for (int j = 0; j < D; ++j) {
        float ujj = 1.f / M[tri(j, j)];
        M[tri(j, j)] = ujj;
#pragma unroll
        for (int i = j + 1; i < D; ++i) {
            float s = 0.f;
#pragma unroll
            for (int p = j; p < i; ++p) s += M[tri(i, p)] * M[tri(p, j)];
            M[tri(i, j)] = -s / M[tri(i, i)];
        }
    }

    const float invs2 = 0.70710678118654752440f;  // folds the 1/2 of maha
    float* Pk = P + k * PK_WORDS;
    unsigned* Pu = (unsigned*)Pk;

    Pk[0] = logf(pi[k]) - hl;
#pragma unroll
    for (int i = 0; i < D; ++i) {
        float acc = 0.f;
#pragma unroll
        for (int j = 0; j <= i; ++j) acc += M[tri(i, j)] * mu[k * D + j];
        Pk[1 + i] = -(acc * invs2);               // store -t'
    }
#pragma unroll
    for (int i = 0; i < D; ++i) {
        const int np = (i + 2) / 2;
#pragma unroll
        for (int p = 0; p < np; ++p) {
            float f0 = M[tri(i, 2 * p)] * invs2;
            float f1 = (2 * p + 1 <= i) ? M[tri(i, 2 * p + 1)] * invs2 : 0.f;
            Pu[17 + rowoff(i) + p] = pack2(f0, f1);
        }
    }
#pragma unroll
    for (int q = 89; q < PK_WORDS; ++q) Pu[q] = 0;
}

// ---------------------------------------------------------------------------
// Main (persistent, params-in-VGPRs): lane = (cluster k = lane&15,
// point-in-group q = lane>>4). Each lane loads ITS cluster's params ONCE
// (~90 VGPRs), then grid-strides over groups of 4 points. No SMEM, no LDS
// data traffic in the loop -- this removes the per-k s_load/lgkmcnt(0)
// serialization that was the invariant ~26 us stall in R2/R3/R6.
// Softmax over k = cross-lane (shfl_xor 1,2,4,8 within 16-lane groups).
// x rows double-buffered in registers to hide load latency.
// ---------------------------------------------------------------------------
__global__ __launch_bounds__(BLK, 3) void gmm_main(
    const float* __restrict__ x, const float* __restrict__ P,
    float* __restrict__ out, int N)
{
    const int tid  = threadIdx.x;
    const int lane = tid & 63;
    const int k    = lane & 15;        // cluster handled by this lane
    const int q    = lane >> 4;        // point-in-group (0..3)

    const long long wid = (long long)blockIdx.x * (BLK / 64) + (tid >> 6);
    const long long nw  = (long long)gridDim.x * (BLK / 64);
    const long long G   = ((long long)N + 3) >> 2;     // point-groups

    // --- persistent per-lane cluster params ---
    const float* __restrict__ Pk = P + k * PK_WORDS;
    const unsigned* __restrict__ Uk = (const unsigned*)(Pk + 17);
    const float ck = Pk[0];
    float nt[D];
#pragma unroll
    for (int i = 0; i < D; ++i) nt[i] = Pk[1 + i];
    unsigned Ur[72];
#pragma unroll
    for (int p = 0; p < 72; ++p) Ur[p] = Uk[p];

    if (wid >= G) return;

    // --- x double-buffer: preload first group ---
    long long g = wid;
    float4 xa0, xa1, xa2, xa3;
    {
        long long n = g * 4 + q;
        if (n >= N) n = N - 1;
        const float4* p = (const float4*)(x + n * D);
        xa0 = p[0]; xa1 = p[1]; xa2 = p[2]; xa3 = p[3];
    }

    while (true) {
        const long long g_next = g + nw;

        // prefetch next group's x row (clamped address; discarded if unused)
        float4 xb0, xb1, xb2, xb3;
        {
            long long n = g_next * 4 + q;
            if (g_next >= G || n >= N) n = 0;
            const float4* p = (const float4*)(x + n * D);
            xb0 = p[0]; xb1 = p[1]; xb2 = p[2]; xb3 = p[3];
        }

        // pack current x to f16 pairs
        h2 xp[8];
        xp[0] = (h2){(_Float16)xa0.x, (_Float16)xa0.y};
        xp[1] = (h2){(_Float16)xa0.z, (_Float16)xa0.w};
        xp[2] = (h2){(_Float16)xa1.x, (_Float16)xa1.y};
        xp[3] = (h2){(_Float16)xa1.z, (_Float16)xa1.w};
        xp[4] = (h2){(_Float16)xa2.x, (_Float16)xa2.y};
        xp[5] = (h2){(_Float16)xa2.z, (_Float16)xa2.w};
        xp[6] = (h2){(_Float16)xa3.x, (_Float16)xa3.y};
        xp[7] = (h2){(_Float16)xa3.z, (_Float16)xa3.w};

        // logit for (point g*4+q, cluster k)
        float acc = 0.f;
#pragma unroll
        for (int i = 0; i < D; ++i) {
            float y = nt[i];
            const int np = (i + 2) / 2;
#pragma unroll
            for (int p = 0; p < np; ++p)
                y = fdot2f(__builtin_bit_cast(h2, Ur[rowoff(i) + p]), xp[p], y);
            acc = fmaf(y, y, acc);
        }
        const float logit = ck - acc;

        // softmax across the 16 cluster-lanes of this point
        float m = logit;
        m = fmaxf(m, __shfl_xor(m, 1));
        m = fmaxf(m, __shfl_xor(m, 2));
        m = fmaxf(m, __shfl_xor(m, 4));
        m = fmaxf(m, __shfl_xor(m, 8));
        const float e = __expf(logit - m);
        float s = e;
        s += __shfl_xor(s, 1);
        s += __shfl_xor(s, 2);
        s += __shfl_xor(s, 4);
        s += __shfl_xor(s, 8);

        const long long n = g * 4 + q;
        if (n < (long long)N)
            out[n * K + k] = e / s;    // wave store: 256 B contiguous

        if (g_next >= G) break;
        g = g_next;
        xa0 = xb0; xa1 = xb1; xa2 = xb2; xa3 = xb3;
    }
}

extern "C" void kernel_launch(void* const* d_in, const int* in_sizes, int n_in,
                              void* d_out, int out_size, void* d_ws, size_t ws_size,
                              hipStream_t stream) {
    const float* x     = (const float*)d_in[0];   // (N, D)
    const float* pi    = (const float*)d_in[1];   // (1, K)
    const float* mu    = (const float*)d_in[2];   // (K, 1, D)
    const float* Sigma = (const float*)d_in[3];   // (K, D, D)
    float* out = (float*)d_out;                   // (N, K)
    const int N = in_sizes[0] / D;

    float* P = (float*)d_ws;                      // K * PK_WORDS dwords

    gmm_prep<<<1, 64, 0, stream>>>(pi, mu, Sigma, P);

    gmm_main<<<GRID, BLK, 0, stream>>>(x, P, out, N);
}

// Round 9
// 131.059 us; speedup vs baseline: 1.0643x; 1.0643x over previous
//
#include <hip/hip_runtime.h>
#include <math.h>

#define D 16
#define K 16
#define BLK 256
#define GRID 1024
#define NFEAT 160        // 144 circular-diag quadratic (d=0..8) + 16 linear
// Feature index f = 32s + 8*quad + j  (s = K-step, quad = lane>>4, j = 0..7):
//   f = 16d + i  (f < 144): z = x_i * x_{(i+d)&15},  d = 2s + (quad>>1), i = 8*(quad&1)+j
//   f = 144 + m: z = x_m  (linear),  m = 8*(quad&1)+j   [s=4, quad>=2]
// Constant feature folded into cv_k = ck - |t'|^2.

typedef __fp16 f16x8 __attribute__((ext_vector_type(8)));   // MFMA operand type
typedef float  f32x4 __attribute__((ext_vector_type(4)));

__host__ __device__ constexpr int tri(int i, int j) { return i * (i + 1) / 2 + j; }

static __device__ __forceinline__ unsigned short f16b(float f) {
    _Float16 h = (_Float16)f;                     // RNE scalar convert
    return __builtin_bit_cast(unsigned short, h);
}
static __device__ __forceinline__ unsigned pkrtz(float a, float b) {
    auto t = __builtin_amdgcn_cvt_pkrtz(a, b);    // __fp16x2, v_cvt_pkrtz_f16_f32
    return __builtin_bit_cast(unsigned, t);
}

// ---------------------------------------------------------------------------
// Prep: one wave; lane k handles cluster k in registers.
// Produces W (K x NFEAT, f16) = GEMM weights and cvals[K] = ck - |t'|^2.
//   U' = chol(Sigma)^-1 / sqrt(2);  A = U'^T U';  t' = U' mu.
//   d=0 weight -A_ii | d=1..7: -2A_ij | d=8 (pair visited twice): -A_ij ;
//   linear: +2 (U'^T t')_m.  A(a,b) computed on the fly (no 136-reg array).
// ---------------------------------------------------------------------------
__global__ __launch_bounds__(64) void gmm_prep(
    const float* __restrict__ pi, const float* __restrict__ mu,
    const float* __restrict__ Sigma, unsigned short* __restrict__ W,
    float* __restrict__ cvals)
{
    const int k = threadIdx.x;
    if (k >= K) return;

    float M[136];   // packed lower-tri
#pragma unroll
    for (int i = 0; i < D; ++i)
#pragma unroll
        for (int j = 0; j <= i; ++j)
            M[tri(i, j)] = Sigma[k * D * D + i * D + j];

    // Cholesky in place.
    float hl = 0.f;
#pragma unroll
    for (int j = 0; j < D; ++j) {
        float s = M[tri(j, j)];
#pragma unroll
        for (int p = 0; p < j; ++p) s -= M[tri(j, p)] * M[tri(j, p)];
        float ljj = sqrtf(s);
        M[tri(j, j)] = ljj;
        hl += logf(ljj);
        float inv = 1.f / ljj;
#pragma unroll
        for (int i = j + 1; i < D; ++i) {
            float t = M[tri(i, j)];
#pragma unroll
            for (int p = 0; p < j; ++p) t -= M[tri(i, p)] * M[tri(j, p)];
            M[tri(i, j)] = t * inv;
        }
    }
    // Invert lower-tri in place.
#pragma unroll
    for (int j = 0; j < D; ++j) {
        float ujj = 1.f / M[tri(j, j)];
        M[tri(j, j)] = ujj;
#pragma unroll
        for (int i = j + 1; i < D; ++i) {
            float s = 0.f;
#pragma unroll
            for (int p = j; p < i; ++p) s += M[tri(i, p)] * M[tri(p, j)];
            M[tri(i, j)] = -s / M[tri(i, i)];
        }
    }
    // Scale: M <- U' = L^-1 / sqrt(2)
    const float invs2 = 0.70710678118654752440f;
#pragma unroll
    for (int t = 0; t < 136; ++t) M[t] *= invs2;

    // t' = U' mu ; gamma = |t'|^2
    float tv[D];
    float gamma = 0.f;
#pragma unroll
    for (int i = 0; i < D; ++i) {
        float a = 0.f;
#pragma unroll
        for (int j = 0; j <= i; ++j) a += M[tri(i, j)] * mu[k * D + j];
        tv[i] = a;
        gamma += a * a;
    }
    cvals[k] = logf(pi[k]) - hl - gamma;

    unsigned short* Wk = W + k * NFEAT;
    // Quadratic features f = 16d + i.
#pragma unroll
    for (int d = 0; d <= 8; ++d)
#pragma unroll
        for (int i = 0; i < D; ++i) {
            const int b = (i + d) & 15;
            const int lo = (i < b) ? i : b;
            const int hi = (i < b) ? b : i;
            float s = 0.f;
#pragma unroll
            for (int t = hi; t < D; ++t) s += M[tri(t, lo)] * M[tri(t, hi)];
            const float w = (d == 0) ? -s : ((d == 8) ? -s : -2.f * s);
            Wk[16 * d + i] = f16b(w);
        }
    // Linear features f = 144 + m: weight = +2 * sum_t t'_t U'[t][m].
#pragma unroll
    for (int m = 0; m < D; ++m) {
        float s = 0.f;
#pragma unroll
        for (int t = m; t < D; ++t) s += tv[t] * M[tri(t, m)];
        Wk[144 + m] = f16b(2.f * s);
    }
}

// ---------------------------------------------------------------------------
// Main: wave processes 16-point tiles (grid-stride). Weights ride as 5
// persistent A-fragments (20 VGPRs/lane). Features built branchlessly from a
// per-lane ROTATED x row (rot = 8*(quad&1), applied at load -> static reg
// indices + one cndmask per feature). 5 MFMAs -> logits in C layout
// (row=cluster, col=point): softmax needs only 4 shuffles; store is one
// coalesced dwordx4 per lane.
// ---------------------------------------------------------------------------
__global__ __launch_bounds__(BLK, 4) void gmm_main(
    const float* __restrict__ x, const unsigned short* __restrict__ W,
    const float* __restrict__ cvals, float* __restrict__ out, int N)
{
    const int tid  = threadIdx.x;
    const int lane = tid & 63;
    const int col  = lane & 15;            // A: cluster row; B: point column
    const int quad = lane >> 4;
    const bool qhi = (quad & 2) != 0;      // quad>>1 as bool
    const int i0   = (quad & 1) * 8;       // x rotation

    // Persistent A-fragments: W[cluster=col][32s + 8*quad + 0..7]
    f16x8 Af[5];
#pragma unroll
    for (int s = 0; s < 5; ++s) {
        const uint4* p = (const uint4*)(W + col * NFEAT + s * 32 + quad * 8);
        uint4 v = *p;
        Af[s] = __builtin_bit_cast(f16x8, v);
    }
    // Epilogue constants for this lane's 4 cluster-rows.
    const f32x4 cv = *(const f32x4*)(cvals + quad * 4);

    const long long T  = ((long long)N + 15) >> 4;
    long long tile     = (long long)blockIdx.x * (BLK / 64) + (tid >> 6);
    const long long nw = (long long)GRID * (BLK / 64);
    if (tile >= T) return;

    // Rotated x row: xr[t] = x[n][(i0+t)&15]  (two shifted float4 pairs).
    float4 xa0, xa1, xa2, xa3;
    {
        long long n = tile * 16 + col;
        if (n >= N) n = N - 1;
        const float* row = x + n * D;
        xa0 = *(const float4*)(row + i0);
        xa1 = *(const float4*)(row + i0 + 4);
        xa2 = *(const float4*)(row + (i0 ^ 8));
        xa3 = *(const float4*)(row + (i0 ^ 8) + 4);
    }

    while (true) {
        const long long tnext = tile + nw;
        // Prefetch next tile's row (double buffer).
        float4 xb0, xb1, xb2, xb3;
        {
            long long n2 = tnext * 16 + col;
            if (tnext >= T || n2 >= (long long)N) n2 = 0;
            const float* row = x + n2 * D;
            xb0 = *(const float4*)(row + i0);
            xb1 = *(const float4*)(row + i0 + 4);
            xb2 = *(const float4*)(row + (i0 ^ 8));
            xb3 = *(const float4*)(row + (i0 ^ 8) + 4);
        }

        const float xr[16] = {xa0.x, xa0.y, xa0.z, xa0.w,
                              xa1.x, xa1.y, xa1.z, xa1.w,
                              xa2.x, xa2.y, xa2.z, xa2.w,
                              xa3.x, xa3.y, xa3.z, xa3.w};

        f32x4 acc = {0.f, 0.f, 0.f, 0.f};
#pragma unroll
        for (int s = 0; s < 5; ++s) {
            float pr[8];
#pragma unroll
            for (int j = 0; j < 8; ++j) {
                float xbv;
                if (s < 4)   // d = 2s + (quad>>1): one cndmask over static regs
                    xbv = qhi ? xr[(j + 2 * s + 1) & 15] : xr[(j + 2 * s) & 15];
                else         // quads 0,1: d=8 ; quads 2,3: linear (x * 1)
                    xbv = qhi ? 1.0f : xr[(j + 8) & 15];
                pr[j] = xr[j] * xbv;
            }
            uint4 bw = {pkrtz(pr[0], pr[1]), pkrtz(pr[2], pr[3]),
                        pkrtz(pr[4], pr[5]), pkrtz(pr[6], pr[7])};
            f16x8 Bf = __builtin_bit_cast(f16x8, bw);
            acc = __builtin_amdgcn_mfma_f32_16x16x32_f16(Af[s], Bf, acc, 0, 0, 0);
        }

        // logits for clusters 4*quad+0..3 of point col.
        f32x4 l = acc + cv;
        float mx = fmaxf(fmaxf(l.x, l.y), fmaxf(l.z, l.w));
        mx = fmaxf(mx, __shfl_xor(mx, 16));
        mx = fmaxf(mx, __shfl_xor(mx, 32));
        float e0 = __expf(l.x - mx), e1 = __expf(l.y - mx);
        float e2 = __expf(l.z - mx), e3 = __expf(l.w - mx);
        float ss = e0 + e1 + e2 + e3;
        ss += __shfl_xor(ss, 16);
        ss += __shfl_xor(ss, 32);
        const float inv = 1.f / ss;

        const long long n = tile * 16 + col;
        if (n < (long long)N) {
            float4* po = (float4*)(out + n * K + quad * 4);
            *po = (float4){e0 * inv, e1 * inv, e2 * inv, e3 * inv};
        }

        if (tnext >= T) break;
        tile = tnext;
        xa0 = xb0; xa1 = xb1; xa2 = xb2; xa3 = xb3;
    }
}

extern "C" void kernel_launch(void* const* d_in, const int* in_sizes, int n_in,
                              void* d_out, int out_size, void* d_ws, size_t ws_size,
                              hipStream_t stream) {
    const float* x     = (const float*)d_in[0];   // (N, D)
    const float* pi    = (const float*)d_in[1];   // (1, K)
    const float* mu    = (const float*)d_in[2];   // (K, 1, D)
    const float* Sigma = (const float*)d_in[3];   // (K, D, D)
    float* out = (float*)d_out;                   // (N, K)
    const int N = in_sizes[0] / D;

    unsigned short* W = (unsigned short*)d_ws;        // K*NFEAT f16 (5120 B)
    float* cvals = (float*)((char*)d_ws + K * NFEAT * sizeof(unsigned short));

    gmm_prep<<<1, 64, 0, stream>>>(pi, mu, Sigma, W, cvals);
    gmm_main<<<GRID, BLK, 0, stream>>>(x, W, cvals, out, N);
}